// Round 9
// baseline (789.346 us; speedup 1.0000x reference)
//
#include <hip/hip_runtime.h>
#include <stdint.h>

#define HW 262144          // 512*512
#define LDIM 33

typedef __bf16 bf16x8 __attribute__((ext_vector_type(8)));
typedef __bf16 bf16x2 __attribute__((ext_vector_type(2)));
typedef float  f32x4  __attribute__((ext_vector_type(4)));

union BF8 { bf16x8 v; unsigned u[4]; };

// native f32->bf16 (RNE) — compiler fuses pairs into v_cvt_pk_bf16_f32
__device__ __forceinline__ unsigned pk2(float a, float b) {
  bf16x2 p; p[0] = (__bf16)a; p[1] = (__bf16)b;
  return __builtin_bit_cast(unsigned, p);
}
// hardware exp2: v_exp_f32 computes 2^x directly
__device__ __forceinline__ float exp2_hw(float x) {
  return __builtin_amdgcn_exp2f(x);
}
// tanh(x) = 1 - 2/(exp2(x*2*log2e)+1)  (log2e folded: one mul, one trans)
__device__ __forceinline__ float tanh_fast(float x) {
  float t = exp2_hw(x * 2.8853900818f);
  return 1.0f - __fdividef(2.0f, t + 1.0f);
}
// gelu_tanh(x) = x - x/(exp(2u)+1), 2u = 1.5957691x + 0.0713548x^3.
// exp(2u) = exp2(x*(2.3021667 + 0.1029425 x^2))  (log2e folded into constants)
__device__ __forceinline__ float gelu_t(float x) {
  float x2 = x * x;
  float p2 = x * fmaf(0.1029425216f, x2, 2.3021667f);
  float r  = __fdividef(1.0f, exp2_hw(p2) + 1.0f);
  return fmaf(-x, r, x);                                    // x(1 - r)
}

// LDS map (65536 B, 512 threads / 8 waves):
//   [0,     32768)  W1 bf16: 128 rows x 256B, 16B group kg stored at (kg ^ (row&15))
//   [32768, 49152)  W2 bf16:  64 rows x 256B, same swizzle
//   [49152, 65536)  per-wave h: 8 waves x 2048B (16 rows x 128B, group swizz kg^(row&7))
//                   holds h1 per half, then h2 for the layer-3 MFMA (wave-local reuse)
// 16 px per wave-iter. Live set target <= 128 total (arch+acc) for launch_bounds(512,4):
// a1(16)+acc1(16)+acc2(16)+acc3(4)+w3a(8)+b1r(8)+b2r(4)+img(3)+lut-prefetch(11)+temps.
// Occupancy: VGPR<=128 -> 4 waves/SIMD; LDS 64KB -> 2 blocks/CU -> 16 waves/CU.
// r8 changes: LUT gathers hoisted into the a1-load shadow (tail no longer eats
// ~250cy of L2 latency per iter), exp2-folded activations (1 fewer mul each).
__global__ __launch_bounds__(512, 4) void local3dlut_kernel(
    const float* __restrict__ img,  const float* __restrict__ ctx,
    const float* __restrict__ lut,  const float* __restrict__ W1,
    const float* __restrict__ b1,   const float* __restrict__ W2,
    const float* __restrict__ b2,   const float* __restrict__ W3,
    const float* __restrict__ b3,   const float* __restrict__ oscp,
    float* __restrict__ out)
{
  __shared__ uint4 smem4[4096];
  char* sm = (char*)smem4;
  const int t    = threadIdx.x;
  const int lane = t & 63;
  const int wv   = t >> 6;        // wave 0..7
  const int n    = lane & 15;
  const int q    = lane >> 4;     // quad 0..3

  // ---- stage W1 (128x128) and W2 (64x128) to LDS as swizzled bf16 ----
  #pragma unroll
  for (int rep = 0; rep < 8; ++rep) {
    int f4 = t + 512 * rep;                 // float4 index 0..4095
    float4 v = ((const float4*)W1)[f4];
    int fi = f4 << 2;
    int o = fi >> 7, k = fi & 127;
    char* dst = sm + o * 256 + (((k >> 3) ^ (o & 15)) << 4) + ((k & 7) << 1);
    *(uint2*)dst = make_uint2(pk2(v.x, v.y), pk2(v.z, v.w));
  }
  #pragma unroll
  for (int rep = 0; rep < 4; ++rep) {
    int f4 = t + 512 * rep;                 // 0..2047
    float4 v = ((const float4*)W2)[f4];
    int fi = f4 << 2;
    int o = fi >> 7, k = fi & 127;
    char* dst = sm + 32768 + o * 256 + (((k >> 3) ^ (o & 15)) << 4) + ((k & 7) << 1);
    *(uint2*)dst = make_uint2(pk2(v.x, v.y), pk2(v.z, v.w));
  }
  __syncthreads();

  // per-lane constants
  float b1r[8];                       // b1[half*4+nt4 feature blocks], col = n
  #pragma unroll
  for (int i = 0; i < 8; ++i) b1r[i] = b1[i * 16 + n];
  float b2r[4];                       // b2[nt2*16 + n] (unswapped acc2 cols = feat2)
  #pragma unroll
  for (int i = 0; i < 4; ++i) b2r[i] = b2[i * 16 + n];
  // W3 padded 16x64 as a permanent A-fragment pair (rows 3..15 zero): lane (n,q)
  // holds A[row=n][k = ks3*32 + q*8 + j], j=0..7
  BF8 w3a[2];
  #pragma unroll
  for (int ks3 = 0; ks3 < 2; ++ks3) {
    #pragma unroll
    for (int m = 0; m < 4; ++m) {
      float e0 = 0.f, e1 = 0.f;
      if (n < 3) {
        e0 = W3[n * 64 + ks3 * 32 + q * 8 + 2 * m];
        e1 = W3[n * 64 + ks3 * 32 + q * 8 + 2 * m + 1];
      }
      w3a[ks3].u[m] = pk2(e0, e1);
    }
  }
  const float b3a0 = b3[0], b3a1 = b3[1], b3a2 = b3[2];
  const float osc  = oscp[0];

  const int p0   = blockIdx.x * 1024;       // 1024 px per block, never crosses batch b
  const int bi   = p0 >> 18;
  const int sblk = p0 & (HW - 1);
  const float* ctxB = ctx + (size_t)bi * ((size_t)128 * HW);
  const float* imgB = img + (size_t)bi * ((size_t)3 * HW);
  float*       outB = out + (size_t)bi * ((size_t)3 * HW);
  char* hb = sm + 49152 + wv * 2048;

  #pragma unroll 1
  for (int it = 0; it < 8; ++it) {
    const int sw = sblk + it * 128 + wv * 16;   // wave's 16-px base in image

    // img loads for this lane's tail pixel (px = n)
    const int spf = sw + n;
    const float rr = imgB[spf];
    const float gg = imgB[HW + spf];
    const float bb = imgB[2 * HW + spf];

    // ---- A1 fragments: ctx, 4 ksteps (global, fragment order) ----
    BF8 a1[4];
    {
      const int sA = sw + n;
      #pragma unroll
      for (int ks = 0; ks < 4; ++ks) {
        const float* cb = ctxB + (size_t)(ks * 32 + q * 8) * HW + sA;
        float v0 = cb[0];
        float v1 = cb[(size_t)1 * HW];
        float v2 = cb[(size_t)2 * HW];
        float v3 = cb[(size_t)3 * HW];
        float v4 = cb[(size_t)4 * HW];
        float v5 = cb[(size_t)5 * HW];
        float v6 = cb[(size_t)6 * HW];
        float v7 = cb[(size_t)7 * HW];
        a1[ks].u[0] = pk2(v0, v1);
        a1[ks].u[1] = pk2(v2, v3);
        a1[ks].u[2] = pk2(v4, v5);
        a1[ks].u[3] = pk2(v6, v7);
      }
    }

    // ---- EARLY LUT: indices + all 8 corner gathers issued here so the L2
    //      latency hides under GEMM1..GEMM3 (values consumed in the tail).
    //      All lanes gather (channel clamped for q==3 -> stays in-bounds). ----
    float fx, fy, fz;
    float c000, c001, c010, c011, c100, c101, c110, c111;
    {
      float gx = fminf(fmaxf(fmaf(rr, 16.f, 16.f), 0.f), 32.f);  // R -> x (b axis)
      float gy = fminf(fmaxf(fmaf(gg, 16.f, 16.f), 0.f), 32.f);  // G -> y (g axis)
      float gz = fminf(fmaxf(fmaf(bb, 16.f, 16.f), 0.f), 32.f);  // B -> z (r axis)
      int x0 = (int)gx, y0 = (int)gy, z0 = (int)gz;
      fx = gx - (float)x0; fy = gy - (float)y0; fz = gz - (float)z0;
      int x1 = min(x0 + 1, 32), y1 = min(y0 + 1, 32), z1 = min(z0 + 1, 32);
      int zy00 = (z0 * LDIM + y0) * LDIM, zy01 = (z0 * LDIM + y1) * LDIM;
      int zy10 = (z1 * LDIM + y0) * LDIM, zy11 = (z1 * LDIM + y1) * LDIM;
      const int chq = (q < 3) ? q : 2;
      const float* L = lut;
      c000 = L[(zy00 + x0) * 3 + chq]; c001 = L[(zy00 + x1) * 3 + chq];
      c010 = L[(zy01 + x0) * 3 + chq]; c011 = L[(zy01 + x1) * 3 + chq];
      c100 = L[(zy10 + x0) * 3 + chq]; c101 = L[(zy10 + x1) * 3 + chq];
      c110 = L[(zy11 + x0) * 3 + chq]; c111 = L[(zy11 + x1) * 3 + chq];
    }

    f32x4 acc2[4];
    #pragma unroll
    for (int j = 0; j < 4; ++j) { f32x4 z = {0.f,0.f,0.f,0.f}; acc2[j] = z; }

    #pragma unroll
    for (int half = 0; half < 2; ++half) {
      // ---- GEMM1 over 4 ntiles of this half (D[px][feat]) ----
      f32x4 acc1[4];
      #pragma unroll
      for (int j = 0; j < 4; ++j) { f32x4 z = {0.f,0.f,0.f,0.f}; acc1[j] = z; }

      #pragma unroll
      for (int ks = 0; ks < 4; ++ks) {
        #pragma unroll
        for (int nt4 = 0; nt4 < 4; ++nt4) {
          int row = (half * 4 + nt4) * 16 + n;
          bf16x8 bw = *(const bf16x8*)(sm + row * 256 + ((((ks << 2) + q) ^ n) << 4));
          acc1[nt4] = __builtin_amdgcn_mfma_f32_16x16x32_bf16(a1[ks].v, bw, acc1[nt4], 0, 0, 0);
        }
      }
      // ---- h1 half: bias + gelu -> bf16 -> LDS (C/D -> A-fragment transpose) ----
      #pragma unroll
      for (int nt4 = 0; nt4 < 4; ++nt4) {
        int fl = nt4 * 16 + n;          // feature within half, 0..63
        int kgf = fl >> 3;
        #pragma unroll
        for (int r = 0; r < 4; ++r) {
          int px = (q << 2) + r;        // 0..15
          float hv = gelu_t(acc1[nt4][r] + b1r[half * 4 + nt4]);
          *(__bf16*)(hb + px * 128 + ((kgf ^ (px & 7)) << 4) + ((fl & 7) << 1)) = (__bf16)hv;
        }
      }
      // ---- GEMM2 partial (unswapped: D[px][feat2]) over this half's 64 feats ----
      #pragma unroll
      for (int ks2 = 0; ks2 < 2; ++ks2) {
        bf16x8 a2 = *(const bf16x8*)(hb + n * 128 + ((((ks2 << 2) + q) ^ (n & 7)) << 4));
        #pragma unroll
        for (int nt2 = 0; nt2 < 4; ++nt2) {
          int row = nt2 * 16 + n;
          int kg2 = half * 8 + (ks2 << 2) + q;
          bf16x8 bw = *(const bf16x8*)(sm + 32768 + row * 256 + ((kg2 ^ n) << 4));
          acc2[nt2] = __builtin_amdgcn_mfma_f32_16x16x32_bf16(a2, bw, acc2[nt2], 0, 0, 0);
        }
      }
    }

    // ---- h2 = gelu(acc2 + b2) -> bf16 -> LDS [px][feat2] (swizzled) ----
    // lane holds h2[px = q*4+r][feat2 = nt2*16+n]
    #pragma unroll
    for (int nt2 = 0; nt2 < 4; ++nt2) {
      int kgW = (nt2 << 1) + (n >> 3);
      #pragma unroll
      for (int r = 0; r < 4; ++r) {
        int px = (q << 2) + r;
        float hv = gelu_t(acc2[nt2][r] + b2r[nt2]);
        *(__bf16*)(hb + px * 128 + ((kgW ^ (px & 7)) << 4) + ((n & 7) << 1)) = (__bf16)hv;
      }
    }

    // ---- GEMM3: D[ch][px] = W3pad(16x64) x h2^T ; B-frag: lane (n,q) reads
    //      feats ks3*32+q*8..+7 at px = n ----
    f32x4 acc3 = {0.f, 0.f, 0.f, 0.f};
    #pragma unroll
    for (int ks3 = 0; ks3 < 2; ++ks3) {
      bf16x8 hf = *(const bf16x8*)(hb + n * 128 + ((((ks3 << 2) + q) ^ (n & 7)) << 4));
      acc3 = __builtin_amdgcn_mfma_f32_16x16x32_bf16(w3a[ks3].v, hf, acc3, 0, 0, 0);
    }
    // rows q*4+r: q=0,r=0..2 hold ch 0..2 for px=n. Redistribute so lane (n, q<3)
    // gets ch=q via 3 bpermutes from lane n (q=0).
    const int ba = n << 2;
    float d0 = __int_as_float(__builtin_amdgcn_ds_bpermute(ba, __float_as_int(acc3[0])));
    float d1 = __int_as_float(__builtin_amdgcn_ds_bpermute(ba, __float_as_int(acc3[1])));
    float d2 = __int_as_float(__builtin_amdgcn_ds_bpermute(ba, __float_as_int(acc3[2])));

    // ---- tail: 48 lanes, ch = q (q<3), px = n; lut corners + offset in-register ----
    if (q < 3) {
      float sel  = (q == 0) ? d0   : ((q == 1) ? d1   : d2);
      float bsel = (q == 0) ? b3a0 : ((q == 1) ? b3a1 : b3a2);
      float ov = tanh_fast(sel + bsel) * osc;

      float c00 = c000 + fx * (c001 - c000);
      float c01 = c010 + fx * (c011 - c010);
      float c10 = c100 + fx * (c101 - c100);
      float c11 = c110 + fx * (c111 - c110);
      float ca  = c00 + fy * (c01 - c00);
      float cb2 = c10 + fy * (c11 - c10);
      float so  = ca + fz * (cb2 - ca);
      outB[q * HW + sw + n] = so * 2.f - 1.f + ov;
    }
  }
}

extern "C" void kernel_launch(void* const* d_in, const int* in_sizes, int n_in,
                              void* d_out, int out_size, void* d_ws, size_t ws_size,
                              hipStream_t stream) {
  const float* img = (const float*)d_in[0];
  const float* ctx = (const float*)d_in[1];
  const float* lut = (const float*)d_in[2];
  const float* W1  = (const float*)d_in[3];
  const float* b1  = (const float*)d_in[4];
  const float* W2  = (const float*)d_in[5];
  const float* b2  = (const float*)d_in[6];
  const float* W3  = (const float*)d_in[7];
  const float* b3  = (const float*)d_in[8];
  const float* osc = (const float*)d_in[9];
  float* out = (float*)d_out;
  // 1024 blocks x 1024 px; 512 threads (8 waves), 64 KB LDS -> 2 blocks/CU;
  // VGPR target <= 128 total -> 16 waves/CU
  local3dlut_kernel<<<dim3(1024), dim3(512), 0, stream>>>(
      img, ctx, lut, W1, b1, W2, b2, W3, b3, osc, out);
}